// Round 1
// baseline (1081.312 us; speedup 1.0000x reference)
//
#include <hip/hip_runtime.h>
#include <cstdint>
#include <cstddef>

#define N_NEU 2048
#define B_SZ  256
#define D_IN  1024
#define T_STEPS 64

typedef _Float16 f16x8 __attribute__((ext_vector_type(8)));
typedef float    f32x4 __attribute__((ext_vector_type(4)));

// ---------------- ws layout (bytes) ----------------
// Wh   : [2048][2048] f16 @ 0        (8 MB)
// Wl   : [2048][2048] f16 @ 8 MB     (8 MB)
// Iext : [256][2048]  f32 @ 16 MB    (2 MB)
// V    : [256][2048]  f32 @ 18 MB    (2 MB)
// S0   : [256][2048]  f16 @ 20 MB    (1 MB)
// S1   : [256][2048]  f16 @ 21 MB    (1 MB)
// total 22 MB

__device__ inline void load_lds16(const void* g, void* l) {
  __builtin_amdgcn_global_load_lds((const __attribute__((address_space(1))) void*)g,
                                   (__attribute__((address_space(3))) void*)l, 16, 0, 0);
}

// Split W_eff = adj*mask into fp16 hi + fp16 lo' (lo' = (w-hi)*4096; w ~= hi + lo'/4096, err ~2^-22)
__global__ __launch_bounds__(256) void k_wsplit(const float* __restrict__ adj,
                                                const float* __restrict__ mask,
                                                _Float16* __restrict__ Wh,
                                                _Float16* __restrict__ Wl) {
  int i = blockIdx.x * blockDim.x + threadIdx.x;
  const int total = N_NEU * N_NEU;
  for (; i < total; i += gridDim.x * blockDim.x) {
    float w = adj[i] * mask[i];
    _Float16 h = (_Float16)w;
    float rem = (w - (float)h) * 4096.0f;
    Wh[i] = h;
    Wl[i] = (_Float16)rem;
  }
}

__global__ __launch_bounds__(256) void k_zero(float* __restrict__ V, _Float16* __restrict__ S0,
                                              _Float16* __restrict__ S1, float* __restrict__ out) {
  int i = blockIdx.x * blockDim.x + threadIdx.x;
  const int total = B_SZ * N_NEU;
  for (; i < total; i += gridDim.x * blockDim.x) {
    V[i] = 0.0f; S0[i] = (_Float16)0.0f; S1[i] = (_Float16)0.0f; out[i] = 0.0f;
  }
}

// I_ext = ext @ W_in^T + b_in, plain fp32 (one-time). Tile 64x64, K-tile 32, transposed LDS.
__global__ __launch_bounds__(256) void k_iext(const float* __restrict__ ext,
                                              const float* __restrict__ Win,
                                              const float* __restrict__ bin,
                                              float* __restrict__ Iext) {
  __shared__ float At[32][68];
  __shared__ float Bt[32][68];
  const int tid = threadIdx.x;
  const int b0 = (blockIdx.x & 3) * 64;
  const int n0 = (blockIdx.x >> 2) * 64;
  const int tx = tid & 15, ty = tid >> 4;
  float acc[4][4] = {};
  for (int kt = 0; kt < D_IN / 32; ++kt) {
    const int k0 = kt * 32;
#pragma unroll
    for (int i = 0; i < 8; ++i) {
      int e = tid + i * 256;
      int kk = e & 31, row = e >> 5;
      At[kk][row] = ext[(size_t)(b0 + row) * D_IN + k0 + kk];
      Bt[kk][row] = Win[(size_t)(n0 + row) * D_IN + k0 + kk];
    }
    __syncthreads();
    for (int kk = 0; kk < 32; ++kk) {
      f32x4 a = *(const f32x4*)&At[kk][ty * 4];
      f32x4 b = *(const f32x4*)&Bt[kk][tx * 4];
#pragma unroll
      for (int i = 0; i < 4; ++i)
#pragma unroll
        for (int j = 0; j < 4; ++j) acc[i][j] += a[i] * b[j];
    }
    __syncthreads();
  }
#pragma unroll
  for (int i = 0; i < 4; ++i)
#pragma unroll
    for (int j = 0; j < 4; ++j)
      Iext[(size_t)(b0 + ty * 4 + i) * N_NEU + n0 + tx * 4 + j] = acc[i][j] + bin[n0 + tx * 4 + j];
}

// One LIF time step: I = S_in @ (Wh + Wl/4096)^T + Iext; V = .9V + I; spike; reset; accumulate.
// Grid 256 blocks (1/CU), tile 64(b) x 32(n), 4 waves (2x2), wave tile 32x16, 16x16x32 f16 MFMA.
__global__ __launch_bounds__(256) void k_step(const _Float16* __restrict__ Wh,
                                              const _Float16* __restrict__ Wl,
                                              const float* __restrict__ Iext,
                                              float* __restrict__ V,
                                              const _Float16* __restrict__ Sin,
                                              _Float16* __restrict__ Sout,
                                              float* __restrict__ out,
                                              int skip_gemm) {
  // Double-buffered LDS: per buffer 16 KB = sA[64][64]f16 (8K) + sWh[32][64] (4K) + sWl[32][64] (4K)
  __shared__ _Float16 smem[16384];
  char* smc = (char*)smem;

  const int tid = threadIdx.x;
  const int lane = tid & 63;
  const int wv = tid >> 6;
  const int wm = wv & 1;       // 2 wave-rows (32 b each)
  const int wn = wv >> 1;      // 2 wave-cols (16 n each)

  // XCD-aware mapping: xcd owns a 256-column W slice (fits its 4MB L2)
  const int bid = blockIdx.x;
  const int xcd = bid & 7;
  const int lg = bid >> 3;          // 0..31
  const int m = lg & 3;             // 4 m-groups
  const int ngl = lg >> 2;          // 0..7
  const int b0 = m * 64;
  const int n0 = (xcd * 8 + ngl) * 32;

  f32x4 acch0{0.f, 0.f, 0.f, 0.f}, acch1{0.f, 0.f, 0.f, 0.f};
  f32x4 accl0{0.f, 0.f, 0.f, 0.f}, accl1{0.f, 0.f, 0.f, 0.f};

  if (!skip_gemm) {
    const unsigned waveB = (unsigned)(tid & 192) * 16u;  // wave*1024

    auto stage = [&](int kc, int buf) {
      const int k0 = kc * 64;
      char* base = smc + buf * 16384;
      // sA: 64 rows x 64 k (pre-swizzled source; LDS written linearly)
#pragma unroll
      for (int r = 0; r < 2; ++r) {
        int row = (tid >> 3) + r * 32;
        int c = tid & 7;
        load_lds16(Sin + (size_t)(b0 + row) * N_NEU + k0 + ((c ^ (row & 7)) << 3),
                   base + r * 4096 + waveB);
      }
      {
        int row = tid >> 3, c = tid & 7;
        load_lds16(Wh + (size_t)(n0 + row) * N_NEU + k0 + ((c ^ (row & 7)) << 3),
                   base + 8192 + waveB);
        load_lds16(Wl + (size_t)(n0 + row) * N_NEU + k0 + ((c ^ (row & 7)) << 3),
                   base + 12288 + waveB);
      }
    };

    stage(0, 0);
    for (int kc = 0; kc < N_NEU / 64; ++kc) {
      __syncthreads();  // drains vmcnt: stage(kc) data ready; all waves done with other buffer
      if (kc + 1 < N_NEU / 64) stage(kc + 1, (kc + 1) & 1);
      const char* cb = smc + (kc & 1) * 16384;
#pragma unroll
      for (int ks = 0; ks < 2; ++ks) {
        const int cch = ks * 4 + (lane >> 4);
        // A frags: rows wm*32 + mf*16 + (lane&15)
        int ra0 = wm * 32 + (lane & 15);
        int ra1 = ra0 + 16;
        f16x8 a0 = *(const f16x8*)(cb + ra0 * 128 + ((cch ^ (ra0 & 7)) << 4));
        f16x8 a1 = *(const f16x8*)(cb + ra1 * 128 + ((cch ^ (ra1 & 7)) << 4));
        // B frags: row wn*16 + (lane&15) in sWh/sWl
        int rb = wn * 16 + (lane & 15);
        f16x8 bh = *(const f16x8*)(cb + 8192 + rb * 128 + ((cch ^ (rb & 7)) << 4));
        f16x8 bl = *(const f16x8*)(cb + 12288 + rb * 128 + ((cch ^ (rb & 7)) << 4));
        acch0 = __builtin_amdgcn_mfma_f32_16x16x32_f16(a0, bh, acch0, 0, 0, 0);
        acch1 = __builtin_amdgcn_mfma_f32_16x16x32_f16(a1, bh, acch1, 0, 0, 0);
        accl0 = __builtin_amdgcn_mfma_f32_16x16x32_f16(a0, bl, accl0, 0, 0, 0);
        accl1 = __builtin_amdgcn_mfma_f32_16x16x32_f16(a1, bl, accl1, 0, 0, 0);
      }
    }
  }

  // Epilogue: fused LIF update. D layout: row=(lane>>4)*4+r (b), col=lane&15 (n)
  const float inv4096 = 1.0f / 4096.0f;
#pragma unroll
  for (int mf = 0; mf < 2; ++mf) {
    f32x4 ah = mf ? acch1 : acch0;
    f32x4 al = mf ? accl1 : accl0;
    const int bb = b0 + wm * 32 + mf * 16 + ((lane >> 4) << 2);
    const int nn = n0 + wn * 16 + (lane & 15);
#pragma unroll
    for (int r = 0; r < 4; ++r) {
      const size_t idx = (size_t)(bb + r) * N_NEU + nn;
      float I = ah[r] + al[r] * inv4096 + Iext[idx];
      float v = 0.9f * V[idx] + I;
      bool sp = (v - 1.0f) >= 0.0f;
      V[idx] = sp ? 0.0f : v;
      Sout[idx] = sp ? (_Float16)1.0f : (_Float16)0.0f;
      out[idx] += sp ? 0.015625f : 0.0f;  // 1/64, exact accumulation
    }
  }
}

extern "C" void kernel_launch(void* const* d_in, const int* in_sizes, int n_in,
                              void* d_out, int out_size, void* d_ws, size_t ws_size,
                              hipStream_t stream) {
  (void)in_sizes; (void)n_in; (void)out_size; (void)ws_size;
  const float* ext  = (const float*)d_in[0];
  const float* Win  = (const float*)d_in[1];
  const float* bin  = (const float*)d_in[2];
  const float* adj  = (const float*)d_in[3];
  const float* mask = (const float*)d_in[4];
  unsigned char* ws = (unsigned char*)d_ws;

  _Float16* Wh   = (_Float16*)(ws);
  _Float16* Wl   = (_Float16*)(ws + (size_t)(8u << 20));
  float*    Iext = (float*)   (ws + (size_t)(16u << 20));
  float*    V    = (float*)   (ws + (size_t)(18u << 20));
  _Float16* S0   = (_Float16*)(ws + (size_t)(20u << 20));
  _Float16* S1   = (_Float16*)(ws + (size_t)(21u << 20));
  float*    out  = (float*)d_out;

  hipLaunchKernelGGL(k_wsplit, dim3(2048), dim3(256), 0, stream, adj, mask, Wh, Wl);
  hipLaunchKernelGGL(k_zero,   dim3(512),  dim3(256), 0, stream, V, S0, S1, out);
  hipLaunchKernelGGL(k_iext,   dim3(128),  dim3(256), 0, stream, ext, Win, bin, Iext);

  for (int t = 0; t < T_STEPS; ++t) {
    const _Float16* Sin  = (t & 1) ? S1 : S0;
    _Float16*       Sout = (t & 1) ? S0 : S1;
    hipLaunchKernelGGL(k_step, dim3(256), dim3(256), 0, stream,
                       Wh, Wl, Iext, V, Sin, Sout, out, (int)(t == 0));
  }
}